// Round 1
// baseline (82.048 us; speedup 1.0000x reference)
//
#include <hip/hip_runtime.h>

#define SS 4096
#define DM 1024

typedef __attribute__((ext_vector_type(4))) float f32x4;
typedef __attribute__((ext_vector_type(8))) __bf16 bf16x8;
typedef __attribute__((ext_vector_type(8))) unsigned short ushort8;
typedef __attribute__((ext_vector_type(4))) unsigned short ushort4v;

#define NEGHUGE -3.0e38f
#define LOG2E 1.44269504f

__device__ __forceinline__ unsigned short f2b(float f) {
    unsigned u = __builtin_bit_cast(unsigned, f);
    u += 0x7fffu + ((u >> 16) & 1u);
    return (unsigned short)(u >> 16);
}

__device__ __forceinline__ f32x4 mfma16(ushort8 a, ushort8 b, f32x4 c) {
    return __builtin_amdgcn_mfma_f32_16x16x32_bf16(
        __builtin_bit_cast(bf16x8, a), __builtin_bit_cast(bf16x8, b), c, 0, 0, 0);
}

// ---------------- kernel 1: convert W (3x [64][1024] f32) -> wb bf16 [192][1024]
__global__ __launch_bounds__(256) void convw_kernel(
    const float* __restrict__ Wq, const float* __restrict__ Wk,
    const float* __restrict__ Wv, unsigned short* __restrict__ wb)
{
    int i = (blockIdx.x * 256 + threadIdx.x) * 4;  // 192*1024 = 196608 elems
    const float* src;
    if (i < 65536) src = Wq + i;
    else if (i < 131072) src = Wk + (i - 65536);
    else src = Wv + (i - 131072);
    f32x4 v = *reinterpret_cast<const f32x4*>(src);
    ushort4v o;
    o[0] = f2b(v[0]); o[1] = f2b(v[1]); o[2] = f2b(v[2]); o[3] = f2b(v[3]);
    *reinterpret_cast<ushort4v*>(wb + i) = o;
}

// ---------------- kernel 2: QKV projection.
// grid 256 (16 rows each), 4 waves split K=1024 into 4x256. MFMA 16x16x32 bf16.
// Writes Qs = (xWq+bq)/8 (bf16), Kb (bf16), VT = V transposed [64][4096] (bf16).
__global__ __launch_bounds__(256) void proj_kernel(
    const float* __restrict__ x, const unsigned short* __restrict__ wb,
    const float* __restrict__ bq, const float* __restrict__ bk, const float* __restrict__ bv,
    unsigned short* __restrict__ Qs, unsigned short* __restrict__ Kb,
    unsigned short* __restrict__ VT)
{
    __shared__ float comb[4 * 3072];  // 48KB: [wave][16 rows][192 cols]
    const int m0 = blockIdx.x * 16;
    const int tid = threadIdx.x;
    const int w = tid >> 6, l = tid & 63;
    const int lc = l & 15;          // frag row/col index
    const int lk = (l >> 4) * 8;    // k sub-offset

    f32x4 acc[12] = {};
    const float* xrow = x + (m0 + lc) * DM;
    const int kbase = w * 256;

    for (int kk = 0; kk < 256; kk += 32) {
        const int k0 = kbase + kk + lk;
        f32x4 u = *reinterpret_cast<const f32x4*>(xrow + k0);
        f32x4 v = *reinterpret_cast<const f32x4*>(xrow + k0 + 4);
        ushort8 a;
        a[0] = f2b(u[0]); a[1] = f2b(u[1]); a[2] = f2b(u[2]); a[3] = f2b(u[3]);
        a[4] = f2b(v[0]); a[5] = f2b(v[1]); a[6] = f2b(v[2]); a[7] = f2b(v[3]);
#pragma unroll
        for (int nf = 0; nf < 12; nf++) {
            ushort8 b = *reinterpret_cast<const ushort8*>(wb + (nf * 16 + lc) * DM + k0);
            acc[nf] = mfma16(a, b, acc[nf]);
        }
    }

    // write partials: C/D layout row=(l>>4)*4+r, col = nf*16 + lc
#pragma unroll
    for (int nf = 0; nf < 12; nf++)
#pragma unroll
        for (int r = 0; r < 4; r++) {
            int row = (l >> 4) * 4 + r;
            comb[w * 3072 + row * 192 + nf * 16 + lc] = acc[nf][r];
        }
    __syncthreads();

    for (int idx = tid; idx < 3072; idx += 256) {
        int row = idx / 192, col = idx % 192;
        float s = comb[idx] + comb[3072 + idx] + comb[6144 + idx] + comb[9216 + idx];
        int grow = m0 + row;
        if (col < 64) {
            s += bq[col];
            Qs[grow * 64 + col] = f2b(s * 0.125f);  // fold 1/sqrt(d_k)=1/8 into Q (exact)
        } else if (col < 128) {
            s += bk[col - 64];
            Kb[grow * 64 + col - 64] = f2b(s);
        } else {
            s += bv[col - 128];
            VT[(col - 128) * SS + grow] = f2b(s);
        }
    }
}

// ---------------- kernel 3: causal flash attention.
// grid 256 blocks: block g handles Q rows [16g,16g+16). 4 waves split the causal
// KV range [0, 16g+16) into 4 chunks of 64-col tiles; in-block LDS combine.
__global__ __launch_bounds__(256) void attn_kernel(
    const unsigned short* __restrict__ Qs, const unsigned short* __restrict__ Kb,
    const unsigned short* __restrict__ VT, float* __restrict__ out)
{
    __shared__ unsigned short plds[4][16 * 64];  // 8KB, per-wave P tiles (XOR-swizzled)
    __shared__ float comb[4][16 * 66];           // 16.5KB, per-wave partials (+m,+l)

    const int g = blockIdx.x;
    const int q0 = g * 16;
    const int tid = threadIdx.x;
    const int w = tid >> 6, l = tid & 63;
    const int lc = l & 15;
    const int lg4 = l >> 4;
    const int lk = lg4 * 8;

    const int tiles = g / 4 + 1;              // ceil((16g+16)/64)
    const int tpw = (tiles + 3) >> 2;
    const int t0 = w * tpw;
    const int t1 = min(tiles, t0 + tpw);

    // Q fragments (Q already scaled by 1/8)
    ushort8 aq0 = *reinterpret_cast<const ushort8*>(Qs + (q0 + lc) * 64 + lk);
    ushort8 aq1 = *reinterpret_cast<const ushort8*>(Qs + (q0 + lc) * 64 + 32 + lk);

    float m4[4], l4[4];
    f32x4 o[4] = {};
#pragma unroll
    for (int r = 0; r < 4; r++) { m4[r] = NEGHUGE; l4[r] = 0.f; }

    char* myp = reinterpret_cast<char*>(plds[w]);

    for (int t = t0; t < t1; ++t) {
        const int kv0 = t * 64;
        f32x4 s[4] = {};
#pragma unroll
        for (int nf = 0; nf < 4; nf++) {
            const unsigned short* kr = Kb + (kv0 + nf * 16 + lc) * 64;
            ushort8 b0 = *reinterpret_cast<const ushort8*>(kr + lk);
            ushort8 b1 = *reinterpret_cast<const ushort8*>(kr + 32 + lk);
            s[nf] = mfma16(aq0, b0, s[nf]);
            s[nf] = mfma16(aq1, b1, s[nf]);
        }
        // causal mask (only diagonal-overlapping tiles need it)
        if (kv0 + 63 > q0) {
#pragma unroll
            for (int nf = 0; nf < 4; nf++)
#pragma unroll
                for (int r = 0; r < 4; r++) {
                    int colg = kv0 + nf * 16 + lc;
                    int rowg = q0 + lg4 * 4 + r;
                    if (colg > rowg) s[nf][r] = NEGHUGE;
                }
        }
        // online softmax (branchless; NEGHUGE pollution is annihilated by weights)
#pragma unroll
        for (int r = 0; r < 4; r++) {
            float mx = fmaxf(fmaxf(s[0][r], s[1][r]), fmaxf(s[2][r], s[3][r]));
            mx = fmaxf(mx, __shfl_xor(mx, 1));
            mx = fmaxf(mx, __shfl_xor(mx, 2));
            mx = fmaxf(mx, __shfl_xor(mx, 4));
            mx = fmaxf(mx, __shfl_xor(mx, 8));
            float mn = fmaxf(m4[r], mx);
            float sc = exp2f((m4[r] - mn) * LOG2E);
            m4[r] = mn;
            float rs = 0.f;
#pragma unroll
            for (int nf = 0; nf < 4; nf++) {
                float p = exp2f((s[nf][r] - mn) * LOG2E);
                s[nf][r] = p;
                rs += p;
            }
            rs += __shfl_xor(rs, 1);
            rs += __shfl_xor(rs, 2);
            rs += __shfl_xor(rs, 4);
            rs += __shfl_xor(rs, 8);
            l4[r] = l4[r] * sc + rs;
            o[0][r] *= sc; o[1][r] *= sc; o[2][r] *= sc; o[3][r] *= sc;
        }
        // P -> LDS (bf16, XOR swizzle byte ^= (row&7)<<4)
#pragma unroll
        for (int nf = 0; nf < 4; nf++)
#pragma unroll
            for (int r = 0; r < 4; r++) {
                int row = lg4 * 4 + r;
                int byte = (row * 128 + (nf * 16 + lc) * 2) ^ ((row & 7) << 4);
                *reinterpret_cast<unsigned short*>(myp + byte) = f2b(s[nf][r]);
            }
        asm volatile("s_waitcnt lgkmcnt(0)" ::: "memory");
        __builtin_amdgcn_sched_barrier(0);
        // PV: A = P from LDS (swizzled b128), B = VT rows (contiguous 16B)
#pragma unroll
        for (int k = 0; k < 2; k++) {
            int rbyte = (lc * 128 + (k * 32 + lk) * 2) ^ ((lc & 7) << 4);
            ushort8 pa = *reinterpret_cast<const ushort8*>(myp + rbyte);
#pragma unroll
            for (int df = 0; df < 4; df++) {
                ushort8 bv = *reinterpret_cast<const ushort8*>(
                    VT + (df * 16 + lc) * SS + kv0 + k * 32 + lk);
                o[df] = mfma16(pa, bv, o[df]);
            }
        }
    }

    // write per-wave partials
#pragma unroll
    for (int df = 0; df < 4; df++)
#pragma unroll
        for (int r = 0; r < 4; r++)
            comb[w][(lg4 * 4 + r) * 66 + df * 16 + lc] = o[df][r];
    if (lc == 0) {
#pragma unroll
        for (int r = 0; r < 4; r++) {
            comb[w][(lg4 * 4 + r) * 66 + 64] = m4[r];
            comb[w][(lg4 * 4 + r) * 66 + 65] = l4[r];
        }
    }
    __syncthreads();

    // combine 4 partials, normalize, write f32 out
    for (int idx = tid; idx < 1024; idx += 256) {
        int row = idx >> 6, col = idx & 63;
        float M = fmaxf(fmaxf(comb[0][row * 66 + 64], comb[1][row * 66 + 64]),
                        fmaxf(comb[2][row * 66 + 64], comb[3][row * 66 + 64]));
        float val = 0.f, den = 0.f;
#pragma unroll
        for (int ww = 0; ww < 4; ww++) {
            float f = exp2f((comb[ww][row * 66 + 64] - M) * LOG2E);
            val += comb[ww][row * 66 + col] * f;
            den += comb[ww][row * 66 + 65] * f;
        }
        out[(q0 + row) * 64 + col] = val / den;
    }
}

extern "C" void kernel_launch(void* const* d_in, const int* in_sizes, int n_in,
                              void* d_out, int out_size, void* d_ws, size_t ws_size,
                              hipStream_t stream) {
    const float* x  = (const float*)d_in[0];
    const float* Wq = (const float*)d_in[1];
    const float* bq = (const float*)d_in[2];
    const float* Wk = (const float*)d_in[3];
    const float* bk = (const float*)d_in[4];
    const float* Wv = (const float*)d_in[5];
    const float* bv = (const float*)d_in[6];
    float* out = (float*)d_out;

    char* ws = (char*)d_ws;
    unsigned short* wb = (unsigned short*)ws;               // 393216 B
    unsigned short* Qs = (unsigned short*)(ws + 393216);    // 524288 B
    unsigned short* Kb = (unsigned short*)(ws + 917504);    // 524288 B
    unsigned short* VT = (unsigned short*)(ws + 1441792);   // 524288 B

    convw_kernel<<<dim3(192), dim3(256), 0, stream>>>(Wq, Wk, Wv, wb);
    proj_kernel<<<dim3(256), dim3(256), 0, stream>>>(x, wb, bq, bk, bv, Qs, Kb, VT);
    attn_kernel<<<dim3(256), dim3(256), 0, stream>>>(Qs, Kb, VT, out);
}

// Round 2
// 56.035 us; speedup vs baseline: 1.4642x; 1.4642x over previous
//
#include <hip/hip_runtime.h>

#define SS 4096
#define DM 1024

typedef __attribute__((ext_vector_type(4))) float f32x4;
typedef __attribute__((ext_vector_type(8))) __bf16 bf16x8;
typedef __attribute__((ext_vector_type(8))) unsigned short ushort8;
typedef __attribute__((ext_vector_type(4))) unsigned short ushort4v;

#define NEGHUGE -3.0e38f
#define LOG2E 1.44269504f

__device__ __forceinline__ unsigned short f2b(float f) {
    unsigned u = __builtin_bit_cast(unsigned, f);
    u += 0x7fffu + ((u >> 16) & 1u);
    return (unsigned short)(u >> 16);
}

__device__ __forceinline__ f32x4 mfma16(ushort8 a, ushort8 b, f32x4 c) {
    return __builtin_amdgcn_mfma_f32_16x16x32_bf16(
        __builtin_bit_cast(bf16x8, a), __builtin_bit_cast(bf16x8, b), c, 0, 0, 0);
}

// ---------------- kernel 1: convert W (3x [64][1024] f32) -> wb bf16 [192][1024]
__global__ __launch_bounds__(256) void convw_kernel(
    const float* __restrict__ Wq, const float* __restrict__ Wk,
    const float* __restrict__ Wv, unsigned short* __restrict__ wb)
{
    int i = (blockIdx.x * 256 + threadIdx.x) * 4;  // 192*1024 = 196608 elems
    const float* src;
    if (i < 65536) src = Wq + i;
    else if (i < 131072) src = Wk + (i - 65536);
    else src = Wv + (i - 131072);
    f32x4 v = *reinterpret_cast<const f32x4*>(src);
    ushort4v o;
    o[0] = f2b(v[0]); o[1] = f2b(v[1]); o[2] = f2b(v[2]); o[3] = f2b(v[3]);
    *reinterpret_cast<ushort4v*>(wb + i) = o;
}

// ---------------- kernel 2: QKV projection.
// grid 256 (16 rows each), 8 waves split K=1024 into 8x128. MFMA 16x16x32 bf16.
// Writes Qs = (xWq+bq)/8 (bf16), Kb (bf16), VT = V transposed [64][4096] (bf16).
__global__ __launch_bounds__(512) void proj_kernel(
    const float* __restrict__ x, const unsigned short* __restrict__ wb,
    const float* __restrict__ bq, const float* __restrict__ bk, const float* __restrict__ bv,
    unsigned short* __restrict__ Qs, unsigned short* __restrict__ Kb,
    unsigned short* __restrict__ VT)
{
    __shared__ float comb[8 * 3072];  // 96KB: [wave][16 rows][192 cols]
    const int m0 = blockIdx.x * 16;
    const int tid = threadIdx.x;
    const int w = tid >> 6, l = tid & 63;
    const int lc = l & 15;          // frag row/col index
    const int lk = (l >> 4) * 8;    // k sub-offset

    f32x4 acc[12] = {};
    const float* xrow = x + (m0 + lc) * DM;
    const int kbase = w * 128;

    for (int kk = 0; kk < 128; kk += 32) {
        const int k0 = kbase + kk + lk;
        f32x4 u = *reinterpret_cast<const f32x4*>(xrow + k0);
        f32x4 v = *reinterpret_cast<const f32x4*>(xrow + k0 + 4);
        ushort8 a;
        a[0] = f2b(u[0]); a[1] = f2b(u[1]); a[2] = f2b(u[2]); a[3] = f2b(u[3]);
        a[4] = f2b(v[0]); a[5] = f2b(v[1]); a[6] = f2b(v[2]); a[7] = f2b(v[3]);
#pragma unroll
        for (int nf = 0; nf < 12; nf++) {
            ushort8 b = *reinterpret_cast<const ushort8*>(wb + (nf * 16 + lc) * DM + k0);
            acc[nf] = mfma16(a, b, acc[nf]);
        }
    }

    // write partials: C/D layout row=(l>>4)*4+r, col = nf*16 + lc
#pragma unroll
    for (int nf = 0; nf < 12; nf++)
#pragma unroll
        for (int r = 0; r < 4; r++) {
            int row = (l >> 4) * 4 + r;
            comb[w * 3072 + row * 192 + nf * 16 + lc] = acc[nf][r];
        }
    __syncthreads();

    for (int idx = tid; idx < 3072; idx += 512) {
        int row = idx / 192, col = idx % 192;
        float s = 0.f;
#pragma unroll
        for (int ww = 0; ww < 8; ww++) s += comb[ww * 3072 + idx];
        int grow = m0 + row;
        if (col < 64) {
            s += bq[col];
            Qs[grow * 64 + col] = f2b(s * 0.125f);  // fold 1/sqrt(d_k)=1/8 into Q (exact)
        } else if (col < 128) {
            s += bk[col - 64];
            Kb[grow * 64 + col - 64] = f2b(s);
        } else {
            s += bv[col - 128];
            VT[(col - 128) * SS + grow] = f2b(s);
        }
    }
}

// ---------------- kernel 3: causal flash attention, split-KV partials.
// grid 1024: block (g = bid>>2, c = bid&3). Group g = Q rows [16g,16g+16).
// The group's causal tile list [0, g/4] is split 16 ways: worker W = c*4+w
// takes tiles W, W+16, W+32, ... Each block combines its 4 waves in LDS and
// writes one unnormalized partial (o[16][64], m[16], l[16]) f32 to `part`.
__global__ __launch_bounds__(256) void attn_part_kernel(
    const unsigned short* __restrict__ Qs, const unsigned short* __restrict__ Kb,
    const unsigned short* __restrict__ VT, float* __restrict__ part)
{
    __shared__ unsigned short plds[4][16 * 64];  // 8KB, per-wave P tiles (XOR-swizzled)
    __shared__ float comb[4][16 * 66];           // 16.5KB, per-wave partials (+m,+l)

    const int bid = blockIdx.x;
    const int g = bid >> 2, c = bid & 3;
    const int q0 = g * 16;
    const int tid = threadIdx.x;
    const int w = tid >> 6, l = tid & 63;
    const int lc = l & 15;
    const int lg4 = l >> 4;
    const int lk = lg4 * 8;

    const int T = g / 4 + 1;        // causal tiles for this group
    const int W0 = c * 4 + w;       // global worker id, stride 16

    // Q fragments (Q already scaled by 1/8)
    ushort8 aq0 = *reinterpret_cast<const ushort8*>(Qs + (q0 + lc) * 64 + lk);
    ushort8 aq1 = *reinterpret_cast<const ushort8*>(Qs + (q0 + lc) * 64 + 32 + lk);

    float m4[4], l4[4];
    f32x4 o[4] = {};
#pragma unroll
    for (int r = 0; r < 4; r++) { m4[r] = NEGHUGE; l4[r] = 0.f; }

    char* myp = reinterpret_cast<char*>(plds[w]);

    for (int t = W0; t < T; t += 16) {
        const int kv0 = t * 64;
        f32x4 s[4] = {};
#pragma unroll
        for (int nf = 0; nf < 4; nf++) {
            const unsigned short* kr = Kb + (kv0 + nf * 16 + lc) * 64;
            ushort8 b0 = *reinterpret_cast<const ushort8*>(kr + lk);
            ushort8 b1 = *reinterpret_cast<const ushort8*>(kr + 32 + lk);
            s[nf] = mfma16(aq0, b0, s[nf]);
            s[nf] = mfma16(aq1, b1, s[nf]);
        }
        // causal mask (only diagonal-overlapping tiles need it)
        if (kv0 + 63 > q0) {
#pragma unroll
            for (int nf = 0; nf < 4; nf++)
#pragma unroll
                for (int r = 0; r < 4; r++) {
                    int colg = kv0 + nf * 16 + lc;
                    int rowg = q0 + lg4 * 4 + r;
                    if (colg > rowg) s[nf][r] = NEGHUGE;
                }
        }
        // online softmax (branchless; NEGHUGE pollution is annihilated by weights)
#pragma unroll
        for (int r = 0; r < 4; r++) {
            float mx = fmaxf(fmaxf(s[0][r], s[1][r]), fmaxf(s[2][r], s[3][r]));
            mx = fmaxf(mx, __shfl_xor(mx, 1));
            mx = fmaxf(mx, __shfl_xor(mx, 2));
            mx = fmaxf(mx, __shfl_xor(mx, 4));
            mx = fmaxf(mx, __shfl_xor(mx, 8));
            float mn = fmaxf(m4[r], mx);
            float sc = exp2f((m4[r] - mn) * LOG2E);
            m4[r] = mn;
            float rs = 0.f;
#pragma unroll
            for (int nf = 0; nf < 4; nf++) {
                float p = exp2f((s[nf][r] - mn) * LOG2E);
                s[nf][r] = p;
                rs += p;
            }
            rs += __shfl_xor(rs, 1);
            rs += __shfl_xor(rs, 2);
            rs += __shfl_xor(rs, 4);
            rs += __shfl_xor(rs, 8);
            l4[r] = l4[r] * sc + rs;
            o[0][r] *= sc; o[1][r] *= sc; o[2][r] *= sc; o[3][r] *= sc;
        }
        // P -> LDS (bf16, XOR swizzle byte ^= (row&7)<<4)
#pragma unroll
        for (int nf = 0; nf < 4; nf++)
#pragma unroll
            for (int r = 0; r < 4; r++) {
                int row = lg4 * 4 + r;
                int byte = (row * 128 + (nf * 16 + lc) * 2) ^ ((row & 7) << 4);
                *reinterpret_cast<unsigned short*>(myp + byte) = f2b(s[nf][r]);
            }
        asm volatile("s_waitcnt lgkmcnt(0)" ::: "memory");
        __builtin_amdgcn_sched_barrier(0);
        // PV: A = P from LDS (swizzled b128), B = VT rows (contiguous 16B)
#pragma unroll
        for (int k = 0; k < 2; k++) {
            int rbyte = (lc * 128 + (k * 32 + lk) * 2) ^ ((lc & 7) << 4);
            ushort8 pa = *reinterpret_cast<const ushort8*>(myp + rbyte);
#pragma unroll
            for (int df = 0; df < 4; df++) {
                ushort8 bv = *reinterpret_cast<const ushort8*>(
                    VT + (df * 16 + lc) * SS + kv0 + k * 32 + lk);
                o[df] = mfma16(pa, bv, o[df]);
            }
        }
    }

    // write per-wave partials
#pragma unroll
    for (int df = 0; df < 4; df++)
#pragma unroll
        for (int r = 0; r < 4; r++)
            comb[w][(lg4 * 4 + r) * 66 + df * 16 + lc] = o[df][r];
    if (lc == 0) {
#pragma unroll
        for (int r = 0; r < 4; r++) {
            comb[w][(lg4 * 4 + r) * 66 + 64] = m4[r];
            comb[w][(lg4 * 4 + r) * 66 + 65] = l4[r];
        }
    }
    __syncthreads();

    // combine 4 wave-partials -> one unnormalized block partial in ws
    float* pp = part + bid * 1056;
    for (int idx = tid; idx < 1024; idx += 256) {
        int row = idx >> 6, col = idx & 63;
        float M = fmaxf(fmaxf(comb[0][row * 66 + 64], comb[1][row * 66 + 64]),
                        fmaxf(comb[2][row * 66 + 64], comb[3][row * 66 + 64]));
        float val = 0.f, den = 0.f;
#pragma unroll
        for (int ww = 0; ww < 4; ww++) {
            float f = exp2f((comb[ww][row * 66 + 64] - M) * LOG2E);
            val += comb[ww][row * 66 + col] * f;
            den += comb[ww][row * 66 + 65] * f;
        }
        pp[row * 66 + col] = val;
        if (col == 0) {
            pp[row * 66 + 64] = M;
            pp[row * 66 + 65] = den;
        }
    }
}

// ---------------- kernel 4: combine the 4 KV-chunk partials per group.
__global__ __launch_bounds__(256) void attn_comb_kernel(
    const float* __restrict__ part, float* __restrict__ out)
{
    const int g = blockIdx.x;
    const int q0 = g * 16;
    const float* p0 = part + (g * 4) * 1056;
    for (int idx = threadIdx.x; idx < 1024; idx += 256) {
        int row = idx >> 6, col = idx & 63;
        float M = NEGHUGE;
#pragma unroll
        for (int cc = 0; cc < 4; cc++)
            M = fmaxf(M, p0[cc * 1056 + row * 66 + 64]);
        float val = 0.f, den = 0.f;
#pragma unroll
        for (int cc = 0; cc < 4; cc++) {
            float f = exp2f((p0[cc * 1056 + row * 66 + 64] - M) * LOG2E);
            val += p0[cc * 1056 + row * 66 + col] * f;
            den += p0[cc * 1056 + row * 66 + 65] * f;
        }
        out[(q0 + row) * 64 + col] = val / den;
    }
}

extern "C" void kernel_launch(void* const* d_in, const int* in_sizes, int n_in,
                              void* d_out, int out_size, void* d_ws, size_t ws_size,
                              hipStream_t stream) {
    const float* x  = (const float*)d_in[0];
    const float* Wq = (const float*)d_in[1];
    const float* bq = (const float*)d_in[2];
    const float* Wk = (const float*)d_in[3];
    const float* bk = (const float*)d_in[4];
    const float* Wv = (const float*)d_in[5];
    const float* bv = (const float*)d_in[6];
    float* out = (float*)d_out;

    char* ws = (char*)d_ws;
    unsigned short* wb = (unsigned short*)ws;               // 393216 B
    unsigned short* Qs = (unsigned short*)(ws + 393216);    // 524288 B
    unsigned short* Kb = (unsigned short*)(ws + 917504);    // 524288 B
    unsigned short* VT = (unsigned short*)(ws + 1441792);   // 524288 B
    float* part = (float*)(ws + 1966080);                   // 1024*1056*4 = 4325376 B

    convw_kernel<<<dim3(192), dim3(256), 0, stream>>>(Wq, Wk, Wv, wb);
    proj_kernel<<<dim3(256), dim3(512), 0, stream>>>(x, wb, bq, bk, bv, Qs, Kb, VT);
    attn_part_kernel<<<dim3(1024), dim3(256), 0, stream>>>(Qs, Kb, VT, part);
    attn_comb_kernel<<<dim3(256), dim3(256), 0, stream>>>(part, out);
}